// Round 1
// baseline (3231.639 us; speedup 1.0000x reference)
//
#include <hip/hip_runtime.h>
#include <math.h>

#define B_ 8
#define C_ 64
#define H_ 192
#define W_ 192
#define HW_ (H_*W_)
#define CHW_ (C_*HW_)
#define TW 32
#define TH 8
#define NPX 256
#define CCH 16

__device__ __forceinline__ float lk(float v){ return v >= 0.f ? v : 0.1f*v; }

// ---------------------------------------------------------------- small hypernet
__global__ __launch_bounds__(256) void k_small(
    const float* __restrict__ d,
    const float* __restrict__ kw1a, const float* __restrict__ kw2a,
    const float* __restrict__ ca1a, const float* __restrict__ ca2a,
    const float* __restrict__ kw1b, const float* __restrict__ kw2b,
    const float* __restrict__ ca1b, const float* __restrict__ ca2b,
    const float* __restrict__ aw1,  const float* __restrict__ aw2,
    float* __restrict__ kern1, float* __restrict__ att1,
    float* __restrict__ kern2, float* __restrict__ att2,
    float* __restrict__ addm)
{
    int b = blockIdx.x, tid = threadIdx.x;
    __shared__ float sd[64], sv[64], su[8];
    if (tid < 64) sd[tid] = d[b*64 + tid];
    __syncthreads();
    // ---- da1 hyper
    if (tid < 64){ float s=0.f; for(int k=0;k<64;k++) s += sd[k]*kw1a[tid*64+k]; sv[tid]=lk(s); }
    if (tid >= 64 && tid < 72){ int r=tid-64; float s=0.f; for(int k=0;k<64;k++) s += sd[k]*ca1a[r*64+k]; su[r]=lk(s); }
    __syncthreads();
    for (int i=tid;i<576;i+=256){ float s=0.f; for(int j=0;j<64;j++) s += sv[j]*kw2a[i*64+j]; kern1[b*576+i]=s; }
    if (tid < 64){ float s=0.f; for(int r=0;r<8;r++) s += su[r]*ca2a[tid*8+r]; att1[b*64+tid]=1.f/(1.f+expf(-s)); }
    __syncthreads();
    // ---- da2 hyper
    if (tid < 64){ float s=0.f; for(int k=0;k<64;k++) s += sd[k]*kw1b[tid*64+k]; sv[tid]=lk(s); }
    if (tid >= 64 && tid < 72){ int r=tid-64; float s=0.f; for(int k=0;k<64;k++) s += sd[k]*ca1b[r*64+k]; su[r]=lk(s); }
    __syncthreads();
    for (int i=tid;i<576;i+=256){ float s=0.f; for(int j=0;j<64;j++) s += sv[j]*kw2b[i*64+j]; kern2[b*576+i]=s; }
    if (tid < 64){ float s=0.f; for(int r=0;r<8;r++) s += su[r]*ca2b[tid*8+r]; att2[b*64+tid]=1.f/(1.f+expf(-s)); }
    __syncthreads();
    // ---- add map
    if (tid < 64){ float s=0.f; for(int k=0;k<64;k++) s += sd[k]*aw1[tid*64+k]; sv[tid]=lk(s); }
    __syncthreads();
    for (int i=tid;i<1024;i+=256){ float s=0.f; for(int j=0;j<64;j++) s += sv[j]*aw2[i*64+j]; addm[b*1024+i]=s; }
}

// ---------------------------------------------------------------- staging helper
__device__ __forceinline__ void stage_tile(const float* __restrict__ in,
                                           float xs[CCH][TH+2][TW+2],
                                           int b, int c0, int h0, int w0, int tid)
{
    const int TOT = CCH*(TH+2)*(TW+2);   // 5440
    for (int e = tid; e < TOT; e += NPX){
        int c   = e / ((TH+2)*(TW+2));
        int rr  = e % ((TH+2)*(TW+2));
        int r   = rr / (TW+2);
        int col = rr % (TW+2);
        int gh = h0 - 1 + r, gw = w0 - 1 + col;
        float v = 0.f;
        if (gh >= 0 && gh < H_ && gw >= 0 && gw < W_)
            v = in[(size_t)(b*C_ + c0 + c)*HW_ + (size_t)gh*W_ + gw];
        xs[c][r][col] = v;
    }
}

// ---------------------------------------------------------------- fused da_conv stage
// out = leaky( cw @ leaky(dwconv(in, kern)) + cb + in*att )
__global__ __launch_bounds__(256) void k_da(
    const float* __restrict__ in, float* __restrict__ out,
    const float* __restrict__ kern, const float* __restrict__ att,
    const float* __restrict__ cw,   const float* __restrict__ cb)
{
    int b  = blockIdx.z;
    int h0 = blockIdx.y * TH;
    int w0 = blockIdx.x * TW;
    int tid = threadIdx.x;
    int ww = tid & 31, hh = tid >> 5;

    __shared__ float xs[CCH][TH+2][TW+2];
    __shared__ float ts[CCH][NPX];

    float acc[C_];
    #pragma unroll
    for (int oc=0; oc<C_; oc++) acc[oc] = cb[oc];

    #pragma unroll 1
    for (int c0=0; c0<C_; c0+=CCH){
        __syncthreads();
        stage_tile(in, xs, b, c0, h0, w0, tid);
        __syncthreads();
        // depthwise 3x3 + inner leaky -> ts
        #pragma unroll 1
        for (int c=0; c<CCH; c++){
            const float* kp = &kern[(size_t)(b*C_ + c0 + c)*9];
            float s = xs[c][hh+0][ww+0]*kp[0] + xs[c][hh+0][ww+1]*kp[1] + xs[c][hh+0][ww+2]*kp[2]
                    + xs[c][hh+1][ww+0]*kp[3] + xs[c][hh+1][ww+1]*kp[4] + xs[c][hh+1][ww+2]*kp[5]
                    + xs[c][hh+2][ww+0]*kp[6] + xs[c][hh+2][ww+1]*kp[7] + xs[c][hh+2][ww+2]*kp[8];
            ts[c][tid] = lk(s);
        }
        __syncthreads();
        // channel mix: acc[oc] += cw[oc][c] * ts[c]
        #pragma unroll 1
        for (int c=0; c<CCH; c++){
            float tv = ts[c][tid];
            const float* cwp = &cw[c0 + c];
            #pragma unroll
            for (int oc=0; oc<C_; oc++)
                acc[oc] = fmaf(cwp[oc*C_], tv, acc[oc]);
        }
    }

    int h = h0 + hh, w = w0 + ww;
    size_t base = (size_t)b*CHW_ + (size_t)h*W_ + w;
    #pragma unroll
    for (int oc=0; oc<C_; oc++){
        float v = acc[oc] + in[base + (size_t)oc*HW_] * att[b*C_ + oc];
        out[base + (size_t)oc*HW_] = lk(v);
    }
}

// ---------------------------------------------------------------- full 3x3 conv
// MODE 0: out = leaky(conv+b) + addmap   (conv1)
// MODE 1: out = conv+b                   (conv2)
// MODE 2: out = conv+b + resid           (conv3)
template<int MODE>
__global__ __launch_bounds__(256) void k_conv(
    const float* __restrict__ in, float* __restrict__ out,
    const float* __restrict__ wgt, const float* __restrict__ bias,
    const float* __restrict__ addm, const float* __restrict__ resid)
{
    int b  = blockIdx.z;
    int h0 = blockIdx.y * TH;
    int w0 = blockIdx.x * TW;
    int tid = threadIdx.x;
    int ww = tid & 31, hh = tid >> 5;

    __shared__ float xs[CCH][TH+2][TW+2];

    float acc[C_];
    #pragma unroll
    for (int oc=0; oc<C_; oc++) acc[oc] = 0.f;

    #pragma unroll 1
    for (int c0=0; c0<C_; c0+=CCH){
        __syncthreads();
        stage_tile(in, xs, b, c0, h0, w0, tid);
        __syncthreads();
        #pragma unroll 1
        for (int c=0; c<CCH; c++){
            float n0 = xs[c][hh+0][ww+0], n1 = xs[c][hh+0][ww+1], n2 = xs[c][hh+0][ww+2];
            float n3 = xs[c][hh+1][ww+0], n4 = xs[c][hh+1][ww+1], n5 = xs[c][hh+1][ww+2];
            float n6 = xs[c][hh+2][ww+0], n7 = xs[c][hh+2][ww+1], n8 = xs[c][hh+2][ww+2];
            const float* wp = &wgt[(size_t)(c0 + c)*9];
            #pragma unroll
            for (int oc=0; oc<C_; oc++){
                const float* wpo = wp + (size_t)oc*(C_*9);
                acc[oc] = fmaf(n0, wpo[0], acc[oc]);
                acc[oc] = fmaf(n1, wpo[1], acc[oc]);
                acc[oc] = fmaf(n2, wpo[2], acc[oc]);
                acc[oc] = fmaf(n3, wpo[3], acc[oc]);
                acc[oc] = fmaf(n4, wpo[4], acc[oc]);
                acc[oc] = fmaf(n5, wpo[5], acc[oc]);
                acc[oc] = fmaf(n6, wpo[6], acc[oc]);
                acc[oc] = fmaf(n7, wpo[7], acc[oc]);
                acc[oc] = fmaf(n8, wpo[8], acc[oc]);
            }
        }
    }

    int h = h0 + hh, w = w0 + ww;
    size_t base = (size_t)b*CHW_ + (size_t)h*W_ + w;
    float addv = 0.f;
    if (MODE == 0) addv = addm[b*1024 + (h/6)*32 + (w/6)];
    #pragma unroll
    for (int oc=0; oc<C_; oc++){
        float v = acc[oc] + bias[oc];
        if (MODE == 0) v = lk(v) + addv;
        if (MODE == 2) v = v + resid[base + (size_t)oc*HW_];
        out[base + (size_t)oc*HW_] = v;
    }
}

// ---------------------------------------------------------------- launch
extern "C" void kernel_launch(void* const* d_in, const int* in_sizes, int n_in,
                              void* d_out, int out_size, void* d_ws, size_t ws_size,
                              hipStream_t stream)
{
    const float* x       = (const float*)d_in[0];
    const float* d       = (const float*)d_in[1];
    const float* da1_kw1 = (const float*)d_in[2];
    const float* da1_kw2 = (const float*)d_in[3];
    const float* da1_cw  = (const float*)d_in[4];
    const float* da1_cb  = (const float*)d_in[5];
    const float* da1_ca1 = (const float*)d_in[6];
    const float* da1_ca2 = (const float*)d_in[7];
    const float* da2_kw1 = (const float*)d_in[8];
    const float* da2_kw2 = (const float*)d_in[9];
    const float* da2_cw  = (const float*)d_in[10];
    const float* da2_cb  = (const float*)d_in[11];
    const float* da2_ca1 = (const float*)d_in[12];
    const float* da2_ca2 = (const float*)d_in[13];
    const float* conv1_w = (const float*)d_in[14];
    const float* conv1_b = (const float*)d_in[15];
    const float* conv2_w = (const float*)d_in[16];
    const float* conv2_b = (const float*)d_in[17];
    const float* conv3_w = (const float*)d_in[18];
    const float* conv3_b = (const float*)d_in[19];
    const float* add_w1  = (const float*)d_in[20];
    const float* add_w2  = (const float*)d_in[21];

    float* ws    = (float*)d_ws;
    float* kern1 = ws;                 // 8*576
    float* att1  = ws + 4608;          // 8*64
    float* kern2 = ws + 5120;          // 8*576
    float* att2  = ws + 9728;          // 8*64
    float* addm  = ws + 10240;         // 8*1024
    float* buf1  = ws + 18432;         // 18,874,368
    float* buf2  = buf1 + (size_t)B_*CHW_;
    float* outp  = (float*)d_out;

    dim3 grid(W_/TW, H_/TH, B_), blk(256);

    k_small<<<B_, 256, 0, stream>>>(d, da1_kw1, da1_kw2, da1_ca1, da1_ca2,
                                    da2_kw1, da2_kw2, da2_ca1, da2_ca2,
                                    add_w1, add_w2, kern1, att1, kern2, att2, addm);
    // out1 = leaky(da_conv1(x))
    k_da<<<grid, blk, 0, stream>>>(x, buf1, kern1, att1, da1_cw, da1_cb);
    // out2 = leaky(conv1(out1)) + add
    k_conv<0><<<grid, blk, 0, stream>>>(buf1, buf2, conv1_w, conv1_b, addm, nullptr);
    // out3 = conv2(out2)
    k_conv<1><<<grid, blk, 0, stream>>>(buf2, buf1, conv2_w, conv2_b, nullptr, nullptr);
    // out4 = leaky(da_conv2(out3))
    k_da<<<grid, blk, 0, stream>>>(buf1, buf2, kern2, att2, da2_cw, da2_cb);
    // out = conv3(out4) + x
    k_conv<2><<<grid, blk, 0, stream>>>(buf2, outp, conv3_w, conv3_b, nullptr, x);

    (void)in_sizes; (void)n_in; (void)out_size; (void)ws_size;
}

// Round 2
// 343.615 us; speedup vs baseline: 9.4048x; 9.4048x over previous
//
#include <hip/hip_runtime.h>
#include <math.h>

#define B_ 8
#define C_ 64
#define H_ 192
#define W_ 192
#define HW_ (H_*W_)

typedef __attribute__((ext_vector_type(8))) short bf16x8;
typedef __attribute__((ext_vector_type(4))) float f32x4;
typedef __attribute__((ext_vector_type(4))) unsigned short u16x4;
typedef __attribute__((ext_vector_type(8))) unsigned short u16x8;
typedef __attribute__((ext_vector_type(4))) unsigned int u32x4;

__device__ __forceinline__ float lk(float v){ return v >= 0.f ? v : 0.1f*v; }
__device__ __forceinline__ float bf2f(unsigned short h){ return __uint_as_float(((unsigned)h)<<16); }
__device__ __forceinline__ unsigned short f2bf(float f){
    unsigned u = __float_as_uint(f);
    return (unsigned short)((u + 0x7fffu + ((u>>16)&1u)) >> 16);
}
__device__ __forceinline__ f32x4 mfma16(bf16x8 a, bf16x8 b, f32x4 c){
    return __builtin_amdgcn_mfma_f32_16x16x32_bf16(a, b, c, 0, 0, 0);
}

// ---------------------------------------------------------------- small hypernet (fp32)
__global__ __launch_bounds__(256) void k_small(
    const float* __restrict__ d,
    const float* __restrict__ kw1a, const float* __restrict__ kw2a,
    const float* __restrict__ ca1a, const float* __restrict__ ca2a,
    const float* __restrict__ kw1b, const float* __restrict__ kw2b,
    const float* __restrict__ ca1b, const float* __restrict__ ca2b,
    const float* __restrict__ aw1,  const float* __restrict__ aw2,
    float* __restrict__ kern1, float* __restrict__ att1,
    float* __restrict__ kern2, float* __restrict__ att2,
    float* __restrict__ addm)
{
    int b = blockIdx.x, tid = threadIdx.x;
    __shared__ float sd[64], sv[64], su[8];
    if (tid < 64) sd[tid] = d[b*64 + tid];
    __syncthreads();
    if (tid < 64){ float s=0.f; for(int k=0;k<64;k++) s += sd[k]*kw1a[tid*64+k]; sv[tid]=lk(s); }
    if (tid >= 64 && tid < 72){ int r=tid-64; float s=0.f; for(int k=0;k<64;k++) s += sd[k]*ca1a[r*64+k]; su[r]=lk(s); }
    __syncthreads();
    for (int i=tid;i<576;i+=256){ float s=0.f; for(int j=0;j<64;j++) s += sv[j]*kw2a[i*64+j]; kern1[b*576+i]=s; }
    if (tid < 64){ float s=0.f; for(int r=0;r<8;r++) s += su[r]*ca2a[tid*8+r]; att1[b*64+tid]=1.f/(1.f+expf(-s)); }
    __syncthreads();
    if (tid < 64){ float s=0.f; for(int k=0;k<64;k++) s += sd[k]*kw1b[tid*64+k]; sv[tid]=lk(s); }
    if (tid >= 64 && tid < 72){ int r=tid-64; float s=0.f; for(int k=0;k<64;k++) s += sd[k]*ca1b[r*64+k]; su[r]=lk(s); }
    __syncthreads();
    for (int i=tid;i<576;i+=256){ float s=0.f; for(int j=0;j<64;j++) s += sv[j]*kw2b[i*64+j]; kern2[b*576+i]=s; }
    if (tid < 64){ float s=0.f; for(int r=0;r<8;r++) s += su[r]*ca2b[tid*8+r]; att2[b*64+tid]=1.f/(1.f+expf(-s)); }
    __syncthreads();
    if (tid < 64){ float s=0.f; for(int k=0;k<64;k++) s += sd[k]*aw1[tid*64+k]; sv[tid]=lk(s); }
    __syncthreads();
    for (int i=tid;i<1024;i+=256){ float s=0.f; for(int j=0;j<64;j++) s += sv[j]*aw2[i*64+j]; addm[b*1024+i]=s; }
}

// ---------------------------------------------------------------- weight prep
// OIHW fp32 [64][64][3][3] -> bf16 [oc][t*64+ic]
__global__ __launch_bounds__(256) void k_wprep3(const float* __restrict__ w, unsigned short* __restrict__ wA){
    int oc = blockIdx.x;
    for (int i = threadIdx.x; i < 576; i += 256){
        int t = i >> 6, ic = i & 63;
        wA[oc*576 + i] = f2bf(w[oc*576 + ic*9 + t]);
    }
}
__global__ __launch_bounds__(256) void k_cast(const float* __restrict__ s, unsigned short* __restrict__ dst, int n){
    int i = blockIdx.x*256 + threadIdx.x;
    if (i < n) dst[i] = f2bf(s[i]);
}

// ---------------------------------------------------------------- MFMA 3x3 conv (implicit GEMM)
// in: NHWC bf16.  MODE 0: out=lk(conv+b)+addm (bf16 NHWC)
//                 MODE 1: out=conv+b          (bf16 NHWC)
//                 MODE 2: out=conv+b+x        (fp32 NCHW)
template<int MODE>
__global__ __launch_bounds__(256) void k_conv(
    const unsigned short* __restrict__ in,
    const unsigned short* __restrict__ wA,
    const float* __restrict__ bias,
    const float* __restrict__ addm,
    const float* __restrict__ xres,
    unsigned short* __restrict__ outb,
    float* __restrict__ outf)
{
    int b = blockIdx.z, h0 = blockIdx.y*16, w0 = blockIdx.x*16;
    int tid = threadIdx.x;
    __shared__ unsigned short xs[18*18*64];   // [pix][ic], 16B-granule XOR swizzle by (pix&7)

    for (int gi = tid; gi < 18*18*8; gi += 256){
        int pix = gi >> 3, j = gi & 7;
        int r = pix/18, col = pix - r*18;
        int gh = h0 - 1 + r, gw = w0 - 1 + col;
        u32x4 v = {0u,0u,0u,0u};
        if (gh >= 0 && gh < H_ && gw >= 0 && gw < W_)
            v = *(const u32x4*)&in[((size_t)(b*HW_ + gh*W_ + gw))*64 + j*8];
        *(u32x4*)&xs[pix*64 + ((j ^ (pix&7))*8)] = v;
    }
    __syncthreads();

    int lane = tid & 63, wv = tid >> 6;
    int n = lane & 15, g = lane >> 4;
    int ochalf = (wv & 1)*32, rowbase = (wv >> 1)*8;

    f32x4 acc[2][8];
    f32x4 zz = {0.f,0.f,0.f,0.f};
    #pragma unroll
    for (int mf=0; mf<2; mf++)
        #pragma unroll
        for (int r=0; r<8; r++) acc[mf][r] = zz;

    const unsigned short* wbase = wA + (size_t)(ochalf + (lane&15))*576 + g*8;

    bf16x8 afr[2][2];
    #pragma unroll
    for (int mf=0; mf<2; mf++)
        #pragma unroll
        for (int kf=0; kf<2; kf++)
            afr[mf][kf] = *(const bf16x8*)(wbase + mf*(16*576) + kf*32);

    #pragma unroll 1
    for (int t=0; t<9; t++){
        bf16x8 nxt[2][2];
        if (t < 8){
            #pragma unroll
            for (int mf=0; mf<2; mf++)
                #pragma unroll
                for (int kf=0; kf<2; kf++)
                    nxt[mf][kf] = *(const bf16x8*)(wbase + mf*(16*576) + (t+1)*64 + kf*32);
        }
        int dy = t/3, dx = t - dy*3;
        #pragma unroll
        for (int r=0; r<8; r++){
            int pix = (rowbase + r + dy)*18 + (n + dx);
            int sw = pix & 7;
            #pragma unroll
            for (int kf=0; kf<2; kf++){
                bf16x8 bfr = *(const bf16x8*)&xs[pix*64 + (((kf*4+g) ^ sw)*8)];
                acc[0][r] = mfma16(afr[0][kf], bfr, acc[0][r]);
                acc[1][r] = mfma16(afr[1][kf], bfr, acc[1][r]);
            }
        }
        if (t < 8){
            #pragma unroll
            for (int mf=0; mf<2; mf++)
                #pragma unroll
                for (int kf=0; kf<2; kf++) afr[mf][kf] = nxt[mf][kf];
        }
    }

    #pragma unroll
    for (int r=0; r<8; r++){
        int h = h0 + rowbase + r, w = w0 + n;
        float addv = 0.f;
        if (MODE == 0) addv = addm[b*1024 + (h/6)*32 + (w/6)];
        #pragma unroll
        for (int mf=0; mf<2; mf++){
            int oc0 = ochalf + mf*16 + g*4;
            f32x4 v = acc[mf][r];
            f32x4 b4 = *(const f32x4*)&bias[oc0];
            if (MODE == 2){
                #pragma unroll
                for (int j=0;j<4;j++){
                    size_t idx = ((size_t)(b*C_ + oc0 + j))*HW_ + (size_t)h*W_ + w;
                    outf[idx] = v[j] + b4[j] + xres[idx];
                }
            } else {
                u16x4 o;
                #pragma unroll
                for (int j=0;j<4;j++){
                    float val = v[j] + b4[j];
                    if (MODE == 0) val = lk(val) + addv;
                    o[j] = f2bf(val);
                }
                *(u16x4*)&outb[((size_t)(b*HW_ + h*W_ + w))*64 + oc0] = o;
            }
        }
    }
}

// ---------------------------------------------------------------- da_conv: depthwise(VALU) + 1x1 mix (MFMA)
// INB 0: input fp32 NCHW; INB 1: input bf16 NHWC. out = lk(mix + cb + x*att), bf16 NHWC.
template<int INB>
__global__ __launch_bounds__(256) void k_da(
    const float* __restrict__ xf,
    const unsigned short* __restrict__ xb,
    const float* __restrict__ kern,
    const float* __restrict__ att,
    const unsigned short* __restrict__ cwA,
    const float* __restrict__ cb,
    unsigned short* __restrict__ outb)
{
    int b = blockIdx.z, h0 = blockIdx.y*8, w0 = blockIdx.x*16;
    int tid = threadIdx.x;
    __shared__ unsigned short xs[10*18*64];   // 180 halo pixels
    __shared__ unsigned short ys[128*64];     // 128 output pixels

    if (INB == 0){
        for (int e = tid; e < 180*64; e += 256){
            int c = e / 180, pix = e - c*180;
            int r = pix/18, col = pix - r*18;
            int gh = h0 - 1 + r, gw = w0 - 1 + col;
            float v = 0.f;
            if (gh>=0 && gh<H_ && gw>=0 && gw<W_)
                v = xf[((size_t)(b*C_ + c))*HW_ + (size_t)gh*W_ + gw];
            xs[pix*64 + (((c>>3) ^ (pix&7))*8) + (c&7)] = f2bf(v);
        }
    } else {
        for (int gi = tid; gi < 180*8; gi += 256){
            int pix = gi >> 3, j = gi & 7;
            int r = pix/18, col = pix - r*18;
            int gh = h0 - 1 + r, gw = w0 - 1 + col;
            u32x4 v = {0u,0u,0u,0u};
            if (gh>=0 && gh<H_ && gw>=0 && gw<W_)
                v = *(const u32x4*)&xb[((size_t)(b*HW_ + gh*W_ + gw))*64 + j*8];
            *(u32x4*)&xs[pix*64 + ((j ^ (pix&7))*8)] = v;
        }
    }
    __syncthreads();

    {   // depthwise 3x3 + inner leaky -> ys (bf16, swizzled)
        int half = tid >> 7, p = tid & 127;
        int rr = p >> 4, cc = p & 15;
        #pragma unroll 1
        for (int q=0; q<4; q++){
            int g8 = half*4 + q;
            float a8[8] = {0.f,0.f,0.f,0.f,0.f,0.f,0.f,0.f};
            #pragma unroll 1
            for (int t=0; t<9; t++){
                int dy = t/3, dx = t - dy*3;
                int spix = (rr+dy)*18 + (cc+dx);
                bf16x8 v = *(const bf16x8*)&xs[spix*64 + ((g8 ^ (spix&7))*8)];
                #pragma unroll
                for (int i=0; i<8; i++)
                    a8[i] = fmaf(bf2f((unsigned short)v[i]), kern[b*576 + (g8*8+i)*9 + t], a8[i]);
            }
            u16x8 o;
            #pragma unroll
            for (int i=0; i<8; i++) o[i] = f2bf(lk(a8[i]));
            *(u16x8*)&ys[p*64 + ((g8 ^ (p&7))*8)] = o;
        }
    }
    __syncthreads();

    int lane = tid & 63, wv = tid >> 6;
    int n = lane & 15, g = lane >> 4;
    int ochalf = (wv & 1)*32, rb = (wv >> 1)*4;

    f32x4 acc[2][4];
    f32x4 zz = {0.f,0.f,0.f,0.f};
    #pragma unroll
    for (int mf=0; mf<2; mf++)
        #pragma unroll
        for (int r=0; r<4; r++) acc[mf][r] = zz;

    bf16x8 afr[2][2];
    #pragma unroll
    for (int mf=0; mf<2; mf++)
        #pragma unroll
        for (int kf=0; kf<2; kf++)
            afr[mf][kf] = *(const bf16x8*)&cwA[(size_t)(ochalf + mf*16 + (lane&15))*64 + kf*32 + g*8];

    #pragma unroll
    for (int r=0; r<4; r++){
        int p2 = (rb + r)*16 + n;
        #pragma unroll
        for (int kf=0; kf<2; kf++){
            bf16x8 bfr = *(const bf16x8*)&ys[p2*64 + (((kf*4+g) ^ (n&7))*8)];
            acc[0][r] = mfma16(afr[0][kf], bfr, acc[0][r]);
            acc[1][r] = mfma16(afr[1][kf], bfr, acc[1][r]);
        }
    }

    #pragma unroll
    for (int mf=0; mf<2; mf++)
    #pragma unroll
    for (int r=0; r<4; r++){
        int rr2 = rb + r;
        int oc0 = ochalf + mf*16 + g*4;
        int h = h0 + rr2, w = w0 + n;
        f32x4 v = acc[mf][r];
        f32x4 cb4 = *(const f32x4*)&cb[oc0];
        f32x4 at4 = *(const f32x4*)&att[b*64 + oc0];
        int spix = (rr2+1)*18 + (n+1);
        int gi2 = (oc0 >> 3) ^ (spix & 7);
        u16x4 xr = *(const u16x4*)&xs[spix*64 + gi2*8 + (oc0 & 7)];
        u16x4 o;
        #pragma unroll
        for (int j=0; j<4; j++){
            float val = v[j] + cb4[j] + bf2f(xr[j])*at4[j];
            o[j] = f2bf(lk(val));
        }
        *(u16x4*)&outb[((size_t)(b*HW_ + h*W_ + w))*64 + oc0] = o;
    }
}

// ---------------------------------------------------------------- launch
extern "C" void kernel_launch(void* const* d_in, const int* in_sizes, int n_in,
                              void* d_out, int out_size, void* d_ws, size_t ws_size,
                              hipStream_t stream)
{
    const float* x       = (const float*)d_in[0];
    const float* d       = (const float*)d_in[1];
    const float* da1_kw1 = (const float*)d_in[2];
    const float* da1_kw2 = (const float*)d_in[3];
    const float* da1_cw  = (const float*)d_in[4];
    const float* da1_cb  = (const float*)d_in[5];
    const float* da1_ca1 = (const float*)d_in[6];
    const float* da1_ca2 = (const float*)d_in[7];
    const float* da2_kw1 = (const float*)d_in[8];
    const float* da2_kw2 = (const float*)d_in[9];
    const float* da2_cw  = (const float*)d_in[10];
    const float* da2_cb  = (const float*)d_in[11];
    const float* da2_ca1 = (const float*)d_in[12];
    const float* da2_ca2 = (const float*)d_in[13];
    const float* conv1_w = (const float*)d_in[14];
    const float* conv1_b = (const float*)d_in[15];
    const float* conv2_w = (const float*)d_in[16];
    const float* conv2_b = (const float*)d_in[17];
    const float* conv3_w = (const float*)d_in[18];
    const float* conv3_b = (const float*)d_in[19];
    const float* add_w1  = (const float*)d_in[20];
    const float* add_w2  = (const float*)d_in[21];

    float* wsf   = (float*)d_ws;
    float* kern1 = wsf;            // 8*576
    float* att1  = wsf + 4608;     // 8*64
    float* kern2 = wsf + 5120;
    float* att2  = wsf + 9728;
    float* addm  = wsf + 10240;    // 8*1024
    unsigned short* wsb  = (unsigned short*)(wsf + 18432);
    unsigned short* wA1  = wsb;
    unsigned short* wA2  = wA1 + 36864;
    unsigned short* wA3  = wA2 + 36864;
    unsigned short* cwA1 = wA3 + 36864;
    unsigned short* cwA2 = cwA1 + 4096;
    unsigned short* buf0 = cwA2 + 4096;
    unsigned short* buf1 = buf0 + (size_t)B_*HW_*64;
    unsigned short* buf2 = buf1 + (size_t)B_*HW_*64;

    k_small<<<B_, 256, 0, stream>>>(d, da1_kw1, da1_kw2, da1_ca1, da1_ca2,
                                    da2_kw1, da2_kw2, da2_ca1, da2_ca2,
                                    add_w1, add_w2, kern1, att1, kern2, att2, addm);
    k_wprep3<<<64, 256, 0, stream>>>(conv1_w, wA1);
    k_wprep3<<<64, 256, 0, stream>>>(conv2_w, wA2);
    k_wprep3<<<64, 256, 0, stream>>>(conv3_w, wA3);
    k_cast<<<16, 256, 0, stream>>>(da1_cw, cwA1, 4096);
    k_cast<<<16, 256, 0, stream>>>(da2_cw, cwA2, 4096);

    dim3 gd(12, 24, 8), gc(12, 12, 8), blk(256);
    k_da<0><<<gd, blk, 0, stream>>>(x, nullptr, kern1, att1, cwA1, da1_cb, buf0);
    k_conv<0><<<gc, blk, 0, stream>>>(buf0, wA1, conv1_b, addm, nullptr, buf1, nullptr);
    k_conv<1><<<gc, blk, 0, stream>>>(buf1, wA2, conv2_b, nullptr, nullptr, buf2, nullptr);
    k_da<1><<<gd, blk, 0, stream>>>(nullptr, buf2, kern2, att2, cwA2, da2_cb, buf0);
    k_conv<2><<<gc, blk, 0, stream>>>(buf0, wA3, conv3_b, nullptr, x, nullptr, (float*)d_out);

    (void)in_sizes; (void)n_in; (void)out_size; (void)ws_size;
}

// Round 3
// 308.921 us; speedup vs baseline: 10.4611x; 1.1123x over previous
//
#include <hip/hip_runtime.h>
#include <math.h>

#define B_ 8
#define C_ 64
#define H_ 192
#define W_ 192
#define HW_ (H_*W_)

typedef __attribute__((ext_vector_type(8))) short bf16x8;
typedef __attribute__((ext_vector_type(4))) float f32x4;
typedef __attribute__((ext_vector_type(4))) unsigned short u16x4;
typedef __attribute__((ext_vector_type(8))) unsigned short u16x8;
typedef __attribute__((ext_vector_type(4))) unsigned int u32x4;

__device__ __forceinline__ float lk(float v){ return v >= 0.f ? v : 0.1f*v; }
__device__ __forceinline__ float bf2f(unsigned short h){ return __uint_as_float(((unsigned)h)<<16); }
__device__ __forceinline__ unsigned short f2bf(float f){
    unsigned u = __float_as_uint(f);
    return (unsigned short)((u + 0x7fffu + ((u>>16)&1u)) >> 16);
}
__device__ __forceinline__ f32x4 mfma16(bf16x8 a, bf16x8 b, f32x4 c){
    return __builtin_amdgcn_mfma_f32_16x16x32_bf16(a, b, c, 0, 0, 0);
}

// ---------------------------------------------------------------- small hypernet (fp32)
__global__ __launch_bounds__(256) void k_small(
    const float* __restrict__ d,
    const float* __restrict__ kw1a, const float* __restrict__ kw2a,
    const float* __restrict__ ca1a, const float* __restrict__ ca2a,
    const float* __restrict__ kw1b, const float* __restrict__ kw2b,
    const float* __restrict__ ca1b, const float* __restrict__ ca2b,
    const float* __restrict__ aw1,  const float* __restrict__ aw2,
    float* __restrict__ kern1, float* __restrict__ att1,
    float* __restrict__ kern2, float* __restrict__ att2,
    float* __restrict__ addm)
{
    int b = blockIdx.x, tid = threadIdx.x;
    __shared__ float sd[64], sv[64], su[8];
    if (tid < 64) sd[tid] = d[b*64 + tid];
    __syncthreads();
    if (tid < 64){ float s=0.f; for(int k=0;k<64;k++) s += sd[k]*kw1a[tid*64+k]; sv[tid]=lk(s); }
    if (tid >= 64 && tid < 72){ int r=tid-64; float s=0.f; for(int k=0;k<64;k++) s += sd[k]*ca1a[r*64+k]; su[r]=lk(s); }
    __syncthreads();
    for (int i=tid;i<576;i+=256){ float s=0.f; for(int j=0;j<64;j++) s += sv[j]*kw2a[i*64+j]; kern1[b*576+i]=s; }
    if (tid < 64){ float s=0.f; for(int r=0;r<8;r++) s += su[r]*ca2a[tid*8+r]; att1[b*64+tid]=1.f/(1.f+expf(-s)); }
    __syncthreads();
    if (tid < 64){ float s=0.f; for(int k=0;k<64;k++) s += sd[k]*kw1b[tid*64+k]; sv[tid]=lk(s); }
    if (tid >= 64 && tid < 72){ int r=tid-64; float s=0.f; for(int k=0;k<64;k++) s += sd[k]*ca1b[r*64+k]; su[r]=lk(s); }
    __syncthreads();
    for (int i=tid;i<576;i+=256){ float s=0.f; for(int j=0;j<64;j++) s += sv[j]*kw2b[i*64+j]; kern2[b*576+i]=s; }
    if (tid < 64){ float s=0.f; for(int r=0;r<8;r++) s += su[r]*ca2b[tid*8+r]; att2[b*64+tid]=1.f/(1.f+expf(-s)); }
    __syncthreads();
    if (tid < 64){ float s=0.f; for(int k=0;k<64;k++) s += sd[k]*aw1[tid*64+k]; sv[tid]=lk(s); }
    __syncthreads();
    for (int i=tid;i<1024;i+=256){ float s=0.f; for(int j=0;j<64;j++) s += sv[j]*aw2[i*64+j]; addm[b*1024+i]=s; }
}

// ---------------------------------------------------------------- weight prep
__global__ __launch_bounds__(256) void k_wprep3(const float* __restrict__ w, unsigned short* __restrict__ wA){
    int oc = blockIdx.x;
    for (int i = threadIdx.x; i < 576; i += 256){
        int t = i >> 6, ic = i & 63;
        wA[oc*576 + i] = f2bf(w[oc*576 + ic*9 + t]);
    }
}
__global__ __launch_bounds__(256) void k_cast(const float* __restrict__ s, unsigned short* __restrict__ dst, int n){
    int i = blockIdx.x*256 + threadIdx.x;
    if (i < n) dst[i] = f2bf(s[i]);
}

// ---------------------------------------------------------------- MFMA 3x3 conv (implicit GEMM)
template<int MODE>
__global__ __launch_bounds__(256) void k_conv(
    const unsigned short* __restrict__ in,
    const unsigned short* __restrict__ wA,
    const float* __restrict__ bias,
    const float* __restrict__ addm,
    const float* __restrict__ xres,
    unsigned short* __restrict__ outb,
    float* __restrict__ outf)
{
    int b = blockIdx.z, h0 = blockIdx.y*16, w0 = blockIdx.x*16;
    int tid = threadIdx.x;
    __shared__ unsigned short xs[18*18*64];

    for (int gi = tid; gi < 18*18*8; gi += 256){
        int pix = gi >> 3, j = gi & 7;
        int r = pix/18, col = pix - r*18;
        int gh = h0 - 1 + r, gw = w0 - 1 + col;
        u32x4 v = {0u,0u,0u,0u};
        if (gh >= 0 && gh < H_ && gw >= 0 && gw < W_)
            v = *(const u32x4*)&in[((size_t)(b*HW_ + gh*W_ + gw))*64 + j*8];
        *(u32x4*)&xs[pix*64 + ((j ^ (pix&7))*8)] = v;
    }
    __syncthreads();

    int lane = tid & 63, wv = tid >> 6;
    int n = lane & 15, g = lane >> 4;
    int ochalf = (wv & 1)*32, rowbase = (wv >> 1)*8;

    f32x4 acc[2][8];
    f32x4 zz = {0.f,0.f,0.f,0.f};
    #pragma unroll
    for (int mf=0; mf<2; mf++)
        #pragma unroll
        for (int r=0; r<8; r++) acc[mf][r] = zz;

    const unsigned short* wbase = wA + (size_t)(ochalf + (lane&15))*576 + g*8;

    bf16x8 afr[2][2];
    #pragma unroll
    for (int mf=0; mf<2; mf++)
        #pragma unroll
        for (int kf=0; kf<2; kf++)
            afr[mf][kf] = *(const bf16x8*)(wbase + mf*(16*576) + kf*32);

    #pragma unroll 1
    for (int t=0; t<9; t++){
        bf16x8 nxt[2][2];
        if (t < 8){
            #pragma unroll
            for (int mf=0; mf<2; mf++)
                #pragma unroll
                for (int kf=0; kf<2; kf++)
                    nxt[mf][kf] = *(const bf16x8*)(wbase + mf*(16*576) + (t+1)*64 + kf*32);
        }
        int dy = t/3, dx = t - dy*3;
        #pragma unroll
        for (int r=0; r<8; r++){
            int pix = (rowbase + r + dy)*18 + (n + dx);
            int sw = pix & 7;
            #pragma unroll
            for (int kf=0; kf<2; kf++){
                bf16x8 bfr = *(const bf16x8*)&xs[pix*64 + (((kf*4+g) ^ sw)*8)];
                acc[0][r] = mfma16(afr[0][kf], bfr, acc[0][r]);
                acc[1][r] = mfma16(afr[1][kf], bfr, acc[1][r]);
            }
        }
        if (t < 8){
            #pragma unroll
            for (int mf=0; mf<2; mf++)
                #pragma unroll
                for (int kf=0; kf<2; kf++) afr[mf][kf] = nxt[mf][kf];
        }
    }

    #pragma unroll
    for (int r=0; r<8; r++){
        int h = h0 + rowbase + r, w = w0 + n;
        float addv = 0.f;
        if (MODE == 0) addv = addm[b*1024 + (h/6)*32 + (w/6)];
        #pragma unroll
        for (int mf=0; mf<2; mf++){
            int oc0 = ochalf + mf*16 + g*4;
            f32x4 v = acc[mf][r];
            f32x4 b4 = *(const f32x4*)&bias[oc0];
            if (MODE == 2){
                #pragma unroll
                for (int j=0;j<4;j++){
                    size_t idx = ((size_t)(b*C_ + oc0 + j))*HW_ + (size_t)h*W_ + w;
                    outf[idx] = v[j] + b4[j] + xres[idx];
                }
            } else {
                u16x4 o;
                #pragma unroll
                for (int j=0;j<4;j++){
                    float val = v[j] + b4[j];
                    if (MODE == 0) val = lk(val) + addv;
                    o[j] = f2bf(val);
                }
                *(u16x4*)&outb[((size_t)(b*HW_ + h*W_ + w))*64 + oc0] = o;
            }
        }
    }
}

// ---------------------------------------------------------------- da_conv: depthwise -> B-frag in regs -> MFMA mix
// Tile 16x8. Lane l of wave wv owns pixel (rr=wv*2+it, cc=l&15), channel chunks g=l>>4 and 4+g.
template<int INB>
__global__ __launch_bounds__(256) void k_da(
    const float* __restrict__ xf,
    const unsigned short* __restrict__ xb,
    const float* __restrict__ kern,
    const float* __restrict__ att,
    const unsigned short* __restrict__ cwA,
    const float* __restrict__ cb,
    unsigned short* __restrict__ outb)
{
    int b = blockIdx.z, h0 = blockIdx.y*8, w0 = blockIdx.x*16;
    int tid = threadIdx.x;
    __shared__ unsigned short xs[180*64];   // 10x18 halo pixels, NHWC, 16B-granule XOR swizzle
    __shared__ float skernT[576];           // [t][ch]

    for (int i = tid; i < 576; i += 256)
        skernT[i] = kern[b*576 + (i & 63)*9 + (i >> 6)];

    if (INB == 0){
        for (int e = tid; e < 180*64; e += 256){
            int c = e / 180, pix = e - c*180;
            int r = pix/18, col = pix - r*18;
            int gh = h0 - 1 + r, gw = w0 - 1 + col;
            float v = 0.f;
            if (gh>=0 && gh<H_ && gw>=0 && gw<W_)
                v = xf[((size_t)(b*C_ + c))*HW_ + (size_t)gh*W_ + gw];
            xs[pix*64 + (((c>>3) ^ (pix&7))*8) + (c&7)] = f2bf(v);
        }
    } else {
        for (int gi = tid; gi < 180*8; gi += 256){
            int pix = gi >> 3, j = gi & 7;
            int r = pix/18, col = pix - r*18;
            int gh = h0 - 1 + r, gw = w0 - 1 + col;
            u32x4 v = {0u,0u,0u,0u};
            if (gh>=0 && gh<H_ && gw>=0 && gw<W_)
                v = *(const u32x4*)&xb[((size_t)(b*HW_ + gh*W_ + gw))*64 + j*8];
            *(u32x4*)&xs[pix*64 + ((j ^ (pix&7))*8)] = v;
        }
    }
    __syncthreads();

    int lane = tid & 63, wv = tid >> 6;
    int cc = lane & 15, g = lane >> 4;

    // A-frags: all 64 oc (4 mf tiles) x K=64 (2 kf)
    bf16x8 afr[4][2];
    #pragma unroll
    for (int mf=0; mf<4; mf++)
        #pragma unroll
        for (int kf=0; kf<2; kf++)
            afr[mf][kf] = *(const bf16x8*)&cwA[(size_t)(mf*16 + cc)*64 + kf*32 + g*8];

    f32x4 acc[2][4];
    f32x4 zz = {0.f,0.f,0.f,0.f};
    #pragma unroll
    for (int it=0; it<2; it++)
        #pragma unroll
        for (int mf=0; mf<4; mf++) acc[it][mf] = zz;

    #pragma unroll
    for (int it=0; it<2; it++){
        int rr = wv*2 + it;
        float a0[8] = {0,0,0,0,0,0,0,0};
        float a1[8] = {0,0,0,0,0,0,0,0};
        #pragma unroll
        for (int t=0; t<9; t++){
            int dy = t/3, dx = t - dy*3;
            int spix = (rr+dy)*18 + (cc+dx);
            int sw = spix & 7;
            bf16x8 v0 = *(const bf16x8*)&xs[spix*64 + ((g     ^ sw)*8)];
            bf16x8 v1 = *(const bf16x8*)&xs[spix*64 + (((4+g) ^ sw)*8)];
            f32x4 ka = *(const f32x4*)&skernT[t*64 + g*8];
            f32x4 kb = *(const f32x4*)&skernT[t*64 + g*8 + 4];
            f32x4 kc = *(const f32x4*)&skernT[t*64 + (4+g)*8];
            f32x4 kd = *(const f32x4*)&skernT[t*64 + (4+g)*8 + 4];
            #pragma unroll
            for (int i=0; i<4; i++){
                a0[i]   = fmaf(bf2f((unsigned short)v0[i]),   ka[i], a0[i]);
                a0[i+4] = fmaf(bf2f((unsigned short)v0[i+4]), kb[i], a0[i+4]);
                a1[i]   = fmaf(bf2f((unsigned short)v1[i]),   kc[i], a1[i]);
                a1[i+4] = fmaf(bf2f((unsigned short)v1[i+4]), kd[i], a1[i+4]);
            }
        }
        bf16x8 pb0, pb1;
        #pragma unroll
        for (int i=0; i<8; i++){
            pb0[i] = (short)f2bf(lk(a0[i]));
            pb1[i] = (short)f2bf(lk(a1[i]));
        }
        #pragma unroll
        for (int mf=0; mf<4; mf++){
            acc[it][mf] = mfma16(afr[mf][0], pb0, acc[it][mf]);
            acc[it][mf] = mfma16(afr[mf][1], pb1, acc[it][mf]);
        }
    }

    #pragma unroll
    for (int it=0; it<2; it++){
        int rr = wv*2 + it;
        int h = h0 + rr, w = w0 + cc;
        int spix = (rr+1)*18 + (cc+1);
        int sw7 = spix & 7;
        #pragma unroll
        for (int mf=0; mf<4; mf++){
            int oc0 = mf*16 + g*4;
            f32x4 v = acc[it][mf];
            f32x4 cb4 = *(const f32x4*)&cb[oc0];
            f32x4 at4 = *(const f32x4*)&att[b*64 + oc0];
            int jg = (oc0 >> 3) ^ sw7;
            u16x4 xr = *(const u16x4*)&xs[spix*64 + jg*8 + (oc0 & 7)];
            u16x4 o;
            #pragma unroll
            for (int j=0; j<4; j++){
                float val = v[j] + cb4[j] + bf2f(xr[j])*at4[j];
                o[j] = f2bf(lk(val));
            }
            *(u16x4*)&outb[((size_t)(b*HW_ + h*W_ + w))*64 + oc0] = o;
        }
    }
}

// ---------------------------------------------------------------- launch
extern "C" void kernel_launch(void* const* d_in, const int* in_sizes, int n_in,
                              void* d_out, int out_size, void* d_ws, size_t ws_size,
                              hipStream_t stream)
{
    const float* x       = (const float*)d_in[0];
    const float* d       = (const float*)d_in[1];
    const float* da1_kw1 = (const float*)d_in[2];
    const float* da1_kw2 = (const float*)d_in[3];
    const float* da1_cw  = (const float*)d_in[4];
    const float* da1_cb  = (const float*)d_in[5];
    const float* da1_ca1 = (const float*)d_in[6];
    const float* da1_ca2 = (const float*)d_in[7];
    const float* da2_kw1 = (const float*)d_in[8];
    const float* da2_kw2 = (const float*)d_in[9];
    const float* da2_cw  = (const float*)d_in[10];
    const float* da2_cb  = (const float*)d_in[11];
    const float* da2_ca1 = (const float*)d_in[12];
    const float* da2_ca2 = (const float*)d_in[13];
    const float* conv1_w = (const float*)d_in[14];
    const float* conv1_b = (const float*)d_in[15];
    const float* conv2_w = (const float*)d_in[16];
    const float* conv2_b = (const float*)d_in[17];
    const float* conv3_w = (const float*)d_in[18];
    const float* conv3_b = (const float*)d_in[19];
    const float* add_w1  = (const float*)d_in[20];
    const float* add_w2  = (const float*)d_in[21];

    float* wsf   = (float*)d_ws;
    float* kern1 = wsf;
    float* att1  = wsf + 4608;
    float* kern2 = wsf + 5120;
    float* att2  = wsf + 9728;
    float* addm  = wsf + 10240;
    unsigned short* wsb  = (unsigned short*)(wsf + 18432);
    unsigned short* wA1  = wsb;
    unsigned short* wA2  = wA1 + 36864;
    unsigned short* wA3  = wA2 + 36864;
    unsigned short* cwA1 = wA3 + 36864;
    unsigned short* cwA2 = cwA1 + 4096;
    unsigned short* buf0 = cwA2 + 4096;
    unsigned short* buf1 = buf0 + (size_t)B_*HW_*64;
    unsigned short* buf2 = buf1 + (size_t)B_*HW_*64;

    k_small<<<B_, 256, 0, stream>>>(d, da1_kw1, da1_kw2, da1_ca1, da1_ca2,
                                    da2_kw1, da2_kw2, da2_ca1, da2_ca2,
                                    add_w1, add_w2, kern1, att1, kern2, att2, addm);
    k_wprep3<<<64, 256, 0, stream>>>(conv1_w, wA1);
    k_wprep3<<<64, 256, 0, stream>>>(conv2_w, wA2);
    k_wprep3<<<64, 256, 0, stream>>>(conv3_w, wA3);
    k_cast<<<16, 256, 0, stream>>>(da1_cw, cwA1, 4096);
    k_cast<<<16, 256, 0, stream>>>(da2_cw, cwA2, 4096);

    dim3 gd(12, 24, 8), gc(12, 12, 8), blk(256);
    k_da<0><<<gd, blk, 0, stream>>>(x, nullptr, kern1, att1, cwA1, da1_cb, buf0);
    k_conv<0><<<gc, blk, 0, stream>>>(buf0, wA1, conv1_b, addm, nullptr, buf1, nullptr);
    k_conv<1><<<gc, blk, 0, stream>>>(buf1, wA2, conv2_b, nullptr, nullptr, buf2, nullptr);
    k_da<1><<<gd, blk, 0, stream>>>(nullptr, buf2, kern2, att2, cwA2, da2_cb, buf0);
    k_conv<2><<<gc, blk, 0, stream>>>(buf0, wA3, conv3_b, nullptr, x, nullptr, (float*)d_out);

    (void)in_sizes; (void)n_in; (void)out_size; (void)ws_size;
}